// Round 15
// baseline (994.556 us; speedup 1.0000x reference)
//
#include <hip/hip_runtime.h>
#include <stdint.h>

typedef __attribute__((ext_vector_type(8))) short short8;
typedef __attribute__((ext_vector_type(4))) float f32x4;
typedef unsigned short u16;
typedef unsigned int u32;
typedef unsigned long long u64;

#define LQ 2048
#define LK 2048
#define RDIM 2048
#define HID 1024
#define NH 16
#define DH 64
// 0.125 * log2(e): softmax computed in base-2 domain
#define S2SCALE 0.1803368801111204f

__device__ __forceinline__ float bf2f(u16 u){
  union { unsigned int i; float f; } v; v.i = ((unsigned int)u) << 16; return v.f;
}
__device__ __forceinline__ u16 f2bf(float f){
  union { float f; unsigned int i; } v; v.f = f;
  unsigned int r = v.i + 0x7fffu + ((v.i >> 16) & 1u);
  return (u16)(r >> 16);
}
__device__ __forceinline__ f32x4 fzero(){ f32x4 z = {0.0f, 0.0f, 0.0f, 0.0f}; return z; }

// ---------------- dtype detection ----------------
__global__ void k_detect(const u32* __restrict__ q, const u32* __restrict__ idxw,
                         int* __restrict__ flags){
  int t = threadIdx.x;  // 64 threads
  u32 w = q[t];
  int b = (w >> 7) & 0xFF;
  unsigned long long mb = __ballot(b >= 100 && b <= 140);
  u32 hi = idxw[2 * t + 1];
  unsigned long long mi = __ballot(hi == 0u);
  if (t == 0){
    flags[0] = (__popcll(mb) >= 48) ? 1 : 0;
    flags[1] = (__popcll(mi) == 64) ? 1 : 0;
  }
}

// ---------------- batched canonicalize: float tensors -> bf16 ----------------
struct Seg { const void* src; u16* dst; int n4; };
struct SegPack { Seg s[8]; };
__global__ void k_ingestN(SegPack p, const int* __restrict__ flags){
  int f = flags[0];
  Seg sg = p.s[blockIdx.y];
  int stride = gridDim.x * blockDim.x;
  for (int i = blockIdx.x * blockDim.x + threadIdx.x; i < sg.n4; i += stride){
    if (f){
      reinterpret_cast<uint2*>(sg.dst)[i] = reinterpret_cast<const uint2*>(sg.src)[i];
    } else {
      float4 v = reinterpret_cast<const float4*>(sg.src)[i];
      union { u16 h[4]; uint2 u; } t;
      t.h[0] = f2bf(v.x); t.h[1] = f2bf(v.y); t.h[2] = f2bf(v.z); t.h[3] = f2bf(v.w);
      reinterpret_cast<uint2*>(sg.dst)[i] = t.u;
    }
  }
}

// ---------------- fused weight ingest + transpose (5 planes) ----------------
struct WPack { const void* src[5]; u16* dst[5]; };
__global__ void k_wtrans(WPack p, const int* __restrict__ flags){
  int f = flags[0];
  const void* W = p.src[blockIdx.z];
  u16* Wt = p.dst[blockIdx.z];
  __shared__ u16 t[64][65];
  int tid = threadIdx.x;
  int bx = blockIdx.x, by = blockIdx.y;
#pragma unroll
  for (int it = 0; it < 16; ++it){
    int id = it * 256 + tid;
    int r = id >> 6, c = id & 63;
    size_t so = (size_t)(by * 64 + r) * HID + bx * 64 + c;
    t[r][c] = f ? ((const u16*)W)[so] : f2bf(((const float*)W)[so]);
  }
  __syncthreads();
#pragma unroll
  for (int it = 0; it < 16; ++it){
    int id = it * 256 + tid;
    int r = id >> 6, c = id & 63;
    Wt[(size_t)(bx * 64 + r) * HID + by * 64 + c] = t[c][r];
  }
}

// ---------------- gather offsets ----------------
__global__ void k_goff(const int* __restrict__ idx, int* __restrict__ goff,
                       const int* __restrict__ flags){
  int i64f = flags[1];
  const size_t N = (size_t)LQ * LK;
  size_t stride = (size_t)gridDim.x * blockDim.x;
  for (size_t t = (size_t)blockIdx.x * blockDim.x + threadIdx.x; t < N; t += stride){
    long long a0, a1;
    if (i64f){
      const long long* ip = (const long long*)idx;
      a0 = ip[t]; a1 = ip[N + t];
    } else {
      a0 = idx[t]; a1 = idx[N + t];
    }
    goff[t] = (int)(a0 * RDIM + a1);
  }
}

// ---------------- GEMM: D = A[M x 1024] @ Bt^T + bias ----------------
__global__ void k_gemm(const u16* __restrict__ A, const u16* __restrict__ Bt,
                       const u16* __restrict__ bias,
                       const u16* __restrict__ add0, const u16* __restrict__ add1,
                       void* __restrict__ D0, u16* __restrict__ D1,
                       int headmajor, const int* __restrict__ oflags){
  __shared__ u16 As[128][72];
  __shared__ u16 Bs[128][72];
  int tid = threadIdx.x;
  int l = tid & 63, w = tid >> 6;
  int lr = l & 15, g = l >> 4;
  int wr = w >> 1, wc = w & 1;
  int outf32 = oflags ? (oflags[0] == 0) : 0;
  f32x4 acc[4][4];
#pragma unroll
  for (int a = 0; a < 4; ++a)
#pragma unroll
    for (int bq_ = 0; bq_ < 4; ++bq_) acc[a][bq_] = fzero();
  const size_t arowg = (size_t)blockIdx.x * 128;
  const size_t browg = (size_t)blockIdx.y * 128;
  for (int kt = 0; kt < HID; kt += 64){
#pragma unroll
    for (int it = 0; it < 4; ++it){
      int id = it * 256 + tid;
      int r = id >> 3, ch = id & 7;
      uint4 va = *reinterpret_cast<const uint4*>(A + (arowg + r) * HID + kt + ch * 8);
      *reinterpret_cast<uint4*>(&As[r][ch * 8]) = va;
      uint4 vb = *reinterpret_cast<const uint4*>(Bt + (browg + r) * HID + kt + ch * 8);
      *reinterpret_cast<uint4*>(&Bs[r][ch * 8]) = vb;
    }
    __syncthreads();
#pragma unroll
    for (int ks = 0; ks < 2; ++ks){
      short8 af[4], bfv[4];
#pragma unroll
      for (int mf = 0; mf < 4; ++mf)
        af[mf] = *reinterpret_cast<const short8*>(&As[wr * 64 + mf * 16 + lr][ks * 32 + 8 * g]);
#pragma unroll
      for (int nf = 0; nf < 4; ++nf)
        bfv[nf] = *reinterpret_cast<const short8*>(&Bs[wc * 64 + nf * 16 + lr][ks * 32 + 8 * g]);
#pragma unroll
      for (int mf = 0; mf < 4; ++mf)
#pragma unroll
        for (int nf = 0; nf < 4; ++nf)
          acc[mf][nf] = __builtin_amdgcn_mfma_f32_16x16x32_bf16(af[mf], bfv[nf], acc[mf][nf], 0, 0, 0);
    }
    __syncthreads();
  }
#pragma unroll
  for (int mf = 0; mf < 4; ++mf)
#pragma unroll
    for (int nf = 0; nf < 4; ++nf){
      int col = (int)browg + wc * 64 + nf * 16 + lr;
      float bcol = bf2f(bias[col]);
      float a0 = add0 ? bf2f(add0[col]) : 0.0f;
      float a1 = add1 ? bf2f(add1[col]) : 0.0f;
#pragma unroll
      for (int reg = 0; reg < 4; ++reg){
        int row = (int)arowg + wr * 64 + mf * 16 + 4 * g + reg;
        float base = acc[mf][nf][reg] + bcol;
        if (headmajor == 2){
          int b = row >> 11, i = row & 2047;
          int n32 = col >> 6, d = col & 63;
          u16* Dx = (n32 < NH) ? (u16*)D0 : D1;
          size_t dst = ((size_t)(b * NH + (n32 & (NH - 1))) * LQ + i) * DH + d;
          Dx[dst] = f2bf(base);
        } else if (headmajor == 1){
          int b = row >> 11, i = row & 2047;
          int n = col >> 6, d = col & 63;
          size_t dst = ((size_t)(b * NH + n) * LQ + i) * DH + d;
          ((u16*)D0)[dst] = f2bf(base + a0);
          if (D1) D1[dst] = f2bf(base + a1);
        } else {
          size_t dst = (size_t)row * HID + col;
          if (outf32) ((float*)D0)[dst] = base;
          else        ((u16*)D0)[dst] = f2bf(base);
        }
      }
    }
}

// ---------------- BD matrix, G=16: direct register->global, no LDS ----------------
// Each wave computes a 16x16 (i,j) quadrant for ALL 16 heads; lane (lr,g) then
// owns complete 32B head-lines for rows 4g+reg and writes them coalesced.
__global__ __launch_bounds__(256) void k_bdfull16(
    const u16* __restrict__ qv, const u16* __restrict__ rr,
    u16* __restrict__ bdf, int bnBase){
  int tid = threadIdx.x;
  int l = tid & 63, w = tid >> 6;
  int lr = l & 15, g = l >> 4;
  int wr = w >> 1, wc = w & 1;
  int i0 = blockIdx.x * 32 + wr * 16;
  int j0 = blockIdx.y * 32 + wc * 16;
  f32x4 acc[16];
#pragma unroll
  for (int h = 0; h < 16; ++h){
    int bn = bnBase + h;
    int b = bn >> 4, n = bn & 15;
    const u16* qb = qv + ((size_t)(b * NH + n) * LQ + i0 + lr) * DH;
    const u16* rb = rr + ((size_t)n * RDIM + j0 + lr) * DH;
    short8 a0 = *reinterpret_cast<const short8*>(qb + 8 * g);
    short8 a1 = *reinterpret_cast<const short8*>(qb + 32 + 8 * g);
    short8 b0 = *reinterpret_cast<const short8*>(rb + 8 * g);
    short8 b1 = *reinterpret_cast<const short8*>(rb + 32 + 8 * g);
    f32x4 z = fzero();
    z = __builtin_amdgcn_mfma_f32_16x16x32_bf16(a0, b0, z, 0, 0, 0);
    z = __builtin_amdgcn_mfma_f32_16x16x32_bf16(a1, b1, z, 0, 0, 0);
    acc[h] = z;
  }
#pragma unroll
  for (int reg = 0; reg < 4; ++reg){
    union { u16 h[16]; uint4 q[2]; } pk;
#pragma unroll
    for (int h = 0; h < 16; ++h) pk.h[h] = f2bf(acc[h][reg]);
    u16* dst = bdf + ((size_t)(i0 + 4 * g + reg) * RDIM + (size_t)(j0 + lr)) * 16;
    *reinterpret_cast<uint4*>(dst) = pk.q[0];
    *reinterpret_cast<uint4*>(dst + 8) = pk.q[1];
  }
}

// ---------------- BD matrix, 8 heads (fallback tier) ----------------
__global__ void k_bdfull8(const u16* __restrict__ qv, const u16* __restrict__ rr,
                          u16* __restrict__ bdf, int bnBase){
  __shared__ u16 tile[32][64][8];   // 32 KB
  int tid = threadIdx.x;
  int l = tid & 63, w = tid >> 6;
  int lr = l & 15, g = l >> 4;
  int i0 = blockIdx.x * 32, j0 = blockIdx.y * 64;
#pragma unroll
  for (int hh = 0; hh < 2; ++hh){
    int g_ = w * 2 + hh;
    int bn = bnBase + g_;
    int b = bn >> 4, n = bn & 15;
    const u16* qb = qv + ((size_t)(b * NH + n) * LQ + i0) * DH;
    const u16* rb = rr + ((size_t)n * RDIM + j0) * DH;
    short8 af[2][2];
#pragma unroll
    for (int mf = 0; mf < 2; ++mf)
#pragma unroll
      for (int ks = 0; ks < 2; ++ks)
        af[mf][ks] = *reinterpret_cast<const short8*>(qb + (size_t)(mf * 16 + lr) * DH + ks * 32 + 8 * g);
    f32x4 acc[2][4];
#pragma unroll
    for (int mf = 0; mf < 2; ++mf)
#pragma unroll
      for (int nf = 0; nf < 4; ++nf) acc[mf][nf] = fzero();
#pragma unroll
    for (int nf = 0; nf < 4; ++nf){
#pragma unroll
      for (int ks = 0; ks < 2; ++ks){
        short8 bb = *reinterpret_cast<const short8*>(rb + (size_t)(nf * 16 + lr) * DH + ks * 32 + 8 * g);
#pragma unroll
        for (int mf = 0; mf < 2; ++mf)
          acc[mf][nf] = __builtin_amdgcn_mfma_f32_16x16x32_bf16(af[mf][ks], bb, acc[mf][nf], 0, 0, 0);
      }
    }
#pragma unroll
    for (int mf = 0; mf < 2; ++mf)
#pragma unroll
      for (int nf = 0; nf < 4; ++nf)
#pragma unroll
        for (int reg = 0; reg < 4; ++reg)
          tile[mf * 16 + 4 * g + reg][nf * 16 + lr][g_] = f2bf(acc[mf][nf][reg]);
  }
  __syncthreads();
#pragma unroll
  for (int e = 0; e < 16; ++e){
    int id = e * 256 + tid;
    int line = id >> 1, part = id & 1;
    int ii = line >> 6, jj = line & 63;
    u64 v = *reinterpret_cast<const u64*>(&tile[ii][jj][part * 4]);
    *reinterpret_cast<u64*>(
        bdf + ((size_t)(i0 + ii) * RDIM + (size_t)(j0 + jj)) * 8 + part * 4) = v;
  }
}

// ---------------- BD matrix generic fallback (tiny ws) ----------------
template<int G>
__global__ void k_bdfull(const u16* __restrict__ qv, const u16* __restrict__ rr,
                         u16* __restrict__ bdf, int bnBase){
  __shared__ u16 tile[16][32][G];
  int tid = threadIdx.x;
  int l = tid & 63, w = tid >> 6;
  int lr = l & 15, g = l >> 4;
  int i0 = blockIdx.x * 16, j0 = blockIdx.y * 32;
  if (w < G){
    int g_ = w;
    int bn = bnBase + g_;
    int b = bn >> 4, n = bn & 15;
    const u16* qb = qv + ((size_t)(b * NH + n) * LQ + i0) * DH;
    const u16* rb = rr + ((size_t)n * RDIM + j0) * DH;
    f32x4 acc2[2];
    acc2[0] = fzero(); acc2[1] = fzero();
#pragma unroll
    for (int ks = 0; ks < 2; ++ks){
      short8 a = *reinterpret_cast<const short8*>(qb + (size_t)lr * DH + ks * 32 + 8 * g);
#pragma unroll
      for (int nf = 0; nf < 2; ++nf){
        short8 bb = *reinterpret_cast<const short8*>(rb + (size_t)(lr + 16 * nf) * DH + ks * 32 + 8 * g);
        acc2[nf] = __builtin_amdgcn_mfma_f32_16x16x32_bf16(a, bb, acc2[nf], 0, 0, 0);
      }
    }
#pragma unroll
    for (int nf = 0; nf < 2; ++nf){
      int jj = lr + 16 * nf;
#pragma unroll
      for (int reg = 0; reg < 4; ++reg)
        tile[4 * g + reg][jj][g_] = f2bf(acc2[nf][reg]);
    }
  }
  __syncthreads();
  constexpr int CHUNKS = 512;
#pragma unroll
  for (int e = 0; e < (CHUNKS * G + 255) / 256 && e * 256 < CHUNKS * G; ++e){
    int id = e * 256 + tid;
    if (id >= CHUNKS * G) break;
    int line = id / G, k = id % G;
    int ii = line >> 5, jj = line & 31;
    bdf[((size_t)(i0 + ii) * RDIM + (size_t)(j0 + jj)) * G + k] = tile[ii][jj][k];
  }
}

// ---------------- gather + lower mask (NT stores); j-range [jBase, jBase+jSpan) ----------------
template<int G>
__global__ void k_gather(const u16* __restrict__ bdf, const int* __restrict__ goff,
                         const u16* __restrict__ lower, u16* __restrict__ bdg,
                         int jBase, int jSpan){
  __shared__ u16 tile[G][16][32];
  int tid = threadIdx.x;
  int i0 = blockIdx.x * 16;
  int j0loc = blockIdx.y * 32;
  int j0 = jBase + j0loc;
#pragma unroll
  for (int it = 0; it < 2; ++it){
    int p = it * 256 + tid;
    int ii = p >> 5, jj = p & 31;
    size_t off = (size_t)(i0 + ii) * LK + (j0 + jj);
    int go = goff[off];
    float lw = bf2f(lower[off]);
    const u16* src = bdf + (size_t)go * G;
    union { uint4 q[2]; u32 w2[8]; u16 h[16]; } uv;
    if (G == 16){
      uv.q[0] = *reinterpret_cast<const uint4*>(src);
      uv.q[1] = *reinterpret_cast<const uint4*>(src + 8);
    } else if (G == 8){
      uv.q[0] = *reinterpret_cast<const uint4*>(src);
    } else if (G == 2){
      uv.w2[0] = *reinterpret_cast<const u32*>(src);
    } else {
      uv.h[0] = *src;
    }
#pragma unroll
    for (int k = 0; k < G; ++k)
      tile[k][ii][jj] = f2bf(bf2f(uv.h[k]) * lw);
  }
  __syncthreads();
  constexpr int CHUNKS = G * 128;
#pragma unroll
  for (int e = 0; e < (CHUNKS + 255) / 256; ++e){
    int id = e * 256 + tid;
    if (CHUNKS < 256 * ((CHUNKS + 255) / 256) && id >= CHUNKS) break;
    int g_ = id >> 7, rem = id & 127;
    int ii = rem >> 3, part = rem & 7;
    u64 v = *reinterpret_cast<const u64*>(&tile[g_][ii][part * 4]);
    __builtin_nontemporal_store(v, reinterpret_cast<u64*>(
        bdg + (size_t)g_ * LQ * jSpan + (size_t)(i0 + ii) * jSpan + j0loc + part * 4));
  }
}

// ---------------- flash attention: multi-pass over j-sections, carried softmax state ----------------
__device__ __forceinline__ void flash_compute(
    int lr, int g,
    const short8& aq0, const short8& aq1,
    f32x4* O, float* mrun, float* lacc,
    u16 (*klds)[72], u16 (*vtlds)[136], u16 (*pldsw)[136]){
  float sv[8][4];
#pragma unroll
  for (int nf = 0; nf < 8; ++nf){
    f32x4 z = fzero();
    short8 bk0 = *reinterpret_cast<const short8*>(&klds[lr + 16 * nf][8 * g]);
    short8 bk1 = *reinterpret_cast<const short8*>(&klds[lr + 16 * nf][32 + 8 * g]);
    z = __builtin_amdgcn_mfma_f32_16x16x32_bf16(aq0, bk0, z, 0, 0, 0);
    z = __builtin_amdgcn_mfma_f32_16x16x32_bf16(aq1, bk1, z, 0, 0, 0);
#pragma unroll
    for (int reg = 0; reg < 4; ++reg){
      float bd = bf2f(pldsw[4 * g + reg][lr + 16 * nf]);   // BD staged in P-LDS slots
      sv[nf][reg] = (z[reg] + bd) * S2SCALE;
    }
  }
  float fs[4];
#pragma unroll
  for (int reg = 0; reg < 4; ++reg){
    float mx = sv[0][reg];
#pragma unroll
    for (int nf = 1; nf < 8; ++nf) mx = fmaxf(mx, sv[nf][reg]);
#pragma unroll
    for (int d = 1; d < 16; d <<= 1) mx = fmaxf(mx, __shfl_xor(mx, d));
    float mnew = fmaxf(mrun[reg], mx);
    fs[reg] = exp2f(mrun[reg] - mnew);
    mrun[reg] = mnew;
    float sumloc = 0.0f;
#pragma unroll
    for (int nf = 0; nf < 8; ++nf){
      sv[nf][reg] = exp2f(sv[nf][reg] - mnew);
      sumloc += sv[nf][reg];
    }
    lacc[reg] = lacc[reg] * fs[reg] + sumloc;
  }
#pragma unroll
  for (int nf = 0; nf < 4; ++nf)
#pragma unroll
    for (int reg = 0; reg < 4; ++reg)
      O[nf][reg] *= fs[reg];
  // P overwrites the (consumed) BD slots — wave-private region, no barrier needed
#pragma unroll
  for (int nf = 0; nf < 8; ++nf)
#pragma unroll
    for (int reg = 0; reg < 4; ++reg)
      pldsw[4 * g + reg][lr + 16 * nf] = f2bf(sv[nf][reg]);
  short8 pa[4];
#pragma unroll
  for (int ks = 0; ks < 4; ++ks)
    pa[ks] = *reinterpret_cast<const short8*>(&pldsw[lr][ks * 32 + 8 * g]);
#pragma unroll
  for (int nf = 0; nf < 4; ++nf){
    int d = lr + 16 * nf;
#pragma unroll
    for (int ks = 0; ks < 4; ++ks){
      int cv = ((ks * 4 + g) ^ (d >> 3)) * 8;   // V^T chunk swizzle read
      short8 bv = *reinterpret_cast<const short8*>(&vtlds[d][cv]);
      O[nf] = __builtin_amdgcn_mfma_f32_16x16x32_bf16(pa[ks], bv, O[nf], 0, 0, 0);
    }
  }
}

// mode bit0 = first pass (init state), bit1 = last pass (finalize -> oo)
__global__ __launch_bounds__(256) void k_flash(
    const u16* __restrict__ qu, const u16* __restrict__ kk,
    const u16* __restrict__ vv, const u16* __restrict__ bdg,
    u16* __restrict__ oo, float* __restrict__ Opart, float2* __restrict__ mlpart,
    int bnBase, int jBase, int jSpan, int mode){
  __shared__ u16 klds[128][72];
  __shared__ u16 vtlds[64][136];
  __shared__ u16 plds[4][16][136];
  int tid = threadIdx.x;
  int l = tid & 63, w = tid >> 6;
  int lr = l & 15, g = l >> 4;
  int gi = blockIdx.x;
  int bn = bnBase + gi;
  int b = bn >> 4, n = bn & 15;
  int i0 = blockIdx.y * 64;
  const u16* qb = qu + ((size_t)bn * LQ + i0 + w * 16) * DH;
  short8 aq0 = *reinterpret_cast<const short8*>(qb + (size_t)lr * DH + 8 * g);
  short8 aq1 = *reinterpret_cast<const short8*>(qb + (size_t)lr * DH + 32 + 8 * g);
  f32x4 O[4];
  float mrun[4], lacc[4];
  if (mode & 1){
#pragma unroll
    for (int nf = 0; nf < 4; ++nf) O[nf] = fzero();
#pragma unroll
    for (int r = 0; r < 4; ++r){ mrun[r] = -1e30f; lacc[r] = 0.0f; }
  } else {
#pragma unroll
    for (int reg = 0; reg < 4; ++reg){
      int i = i0 + w * 16 + 4 * g + reg;
      float2 ml = mlpart[(((size_t)gi * LQ + i) << 4) + lr];
      mrun[reg] = ml.x; lacc[reg] = ml.y;
#pragma unroll
      for (int nf = 0; nf < 4; ++nf)
        O[nf][reg] = Opart[((size_t)gi * LQ + i) * DH + lr + 16 * nf];
    }
  }
  const u16* kbase = kk + (size_t)bn * LK * DH;
  const u16* vbase = vv + (size_t)bn * LK * DH;
  const u16* bdw = bdg + (size_t)gi * LQ * jSpan + (size_t)(i0 + w * 16) * jSpan;
  u16 (*pldsw)[136] = plds[w];
  int brow = l >> 2, bq = l & 3;   // BD cooperative: 16 rows x 4 lane-quads

  uint4 kv[8];   // K (4) + V (4) staging regs
  uint4 bdv[4];  // BD staging regs (wave's 16 rows x 128 local cols)

#define LOADALL(JL_) do { _Pragma("unroll") for (int it_ = 0; it_ < 4; ++it_){ \
    int id_ = it_ * 256 + tid; int r_ = id_ >> 3, ch_ = id_ & 7; \
    kv[it_]     = *reinterpret_cast<const uint4*>(kbase + (size_t)(jBase + (JL_) + r_) * DH + ch_ * 8); \
    kv[4 + it_] = *reinterpret_cast<const uint4*>(vbase + (size_t)(jBase + (JL_) + r_) * DH + ch_ * 8); } \
    _Pragma("unroll") for (int c_ = 0; c_ < 4; ++c_) \
      bdv[c_] = *reinterpret_cast<const uint4*>(bdw + (size_t)brow * jSpan + (JL_) + (c_ * 4 + bq) * 8); } while(0)

#define WRITEALL() do { _Pragma("unroll") for (int it_ = 0; it_ < 4; ++it_){ \
    int id_ = it_ * 256 + tid; int r_ = id_ >> 3, ch_ = id_ & 7; \
    *reinterpret_cast<uint4*>(&klds[r_][ch_ * 8]) = kv[it_]; \
    u16 tmp_[8]; *reinterpret_cast<uint4*>(tmp_) = kv[4 + it_]; \
    int cb_ = r_ ^ (ch_ * 8); \
    _Pragma("unroll") for (int e_ = 0; e_ < 8; ++e_) vtlds[ch_ * 8 + e_][cb_] = tmp_[e_]; } \
    _Pragma("unroll") for (int c_ = 0; c_ < 4; ++c_) \
      *reinterpret_cast<uint4*>(&pldsw[brow][(c_ * 4 + bq) * 8]) = bdv[c_]; } while(0)

  int ntiles = jSpan >> 7;
  LOADALL(0);
  WRITEALL();
  __syncthreads();

  for (int t = 0; t < ntiles; ++t){
    if (t < ntiles - 1) LOADALL((t + 1) * 128);
    flash_compute(lr, g, aq0, aq1, O, mrun, lacc, klds, vtlds, pldsw);
    if (t < ntiles - 1){
      __syncthreads();
      WRITEALL();
      __syncthreads();
    }
  }
#undef LOADALL
#undef WRITEALL

  if (mode & 2){
    float lsum[4];
#pragma unroll
    for (int reg = 0; reg < 4; ++reg){
      float s = lacc[reg];
#pragma unroll
      for (int d = 1; d < 16; d <<= 1) s += __shfl_xor(s, d);
      lsum[reg] = s;
    }
#pragma unroll
    for (int nf = 0; nf < 4; ++nf)
#pragma unroll
      for (int reg = 0; reg < 4; ++reg){
        int i = i0 + w * 16 + 4 * g + reg;
        float vo = O[nf][reg] / lsum[reg];
        oo[((size_t)(b * LQ + i)) * HID + n * DH + lr + 16 * nf] = f2bf(vo);
      }
  } else {
#pragma unroll
    for (int reg = 0; reg < 4; ++reg){
      int i = i0 + w * 16 + 4 * g + reg;
      float2 ml; ml.x = mrun[reg]; ml.y = lacc[reg];
      mlpart[(((size_t)gi * LQ + i) << 4) + lr] = ml;
#pragma unroll
      for (int nf = 0; nf < 4; ++nf)
        Opart[((size_t)gi * LQ + i) * DH + lr + 16 * nf] = O[nf][reg];
    }
  }
}

extern "C" void kernel_launch(void* const* d_in, const int* in_sizes, int n_in,
                              void* d_out, int out_size, void* d_ws, size_t ws_size,
                              hipStream_t stream){
  const void* query = d_in[0];
  const void* value = d_in[1];
  const void* pos   = d_in[2];
  const void* uw    = d_in[3];
  const void* vw    = d_in[4];
  const int* idx    = (const int*)d_in[5];
  const void* lower = d_in[6];
  const void* Wq = d_in[7];  const void* bq = d_in[8];
  const void* Wk = d_in[9];  const void* bk = d_in[10];
  const void* Wv = d_in[11]; const void* bv = d_in[12];
  const void* Wr = d_in[13]; const void* br = d_in[14];
  const void* Wo = d_in[15]; const void* bo = d_in[16];
  (void)in_sizes; (void)n_in; (void)out_size;

  char* ws = (char*)d_ws;
  const size_t MB = (size_t)1 << 20;
  // ---- layout: fixed region [0,83); bdf [83,211); bdg [211, ...) ----
  u16* cquery = (u16*)(ws + 0 * MB);    // [0,8)   dead after projections
  u16* cvalue = (u16*)(ws + 8 * MB);    // [8,16)  dead after projections
  int* goff   = (int*)(ws + 0 * MB);    // [0,16)  overlays post-projection
  u16* clower = (u16*)(ws + 16 * MB);   // [16,24)
  char* sm = ws + 24 * MB;              // [24,25)
  u16* cuw = (u16*)(sm + 0 * 4096);
  u16* cvw = (u16*)(sm + 1 * 4096);
  u16* cbq = (u16*)(sm + 2 * 4096);
  u16* cbk = (u16*)(sm + 3 * 4096);
  u16* cbv = cbk + 1024;
  u16* cbr = (u16*)(sm + 5 * 4096);
  u16* cbo = (u16*)(sm + 6 * 4096);
  int* flags = (int*)(sm + 7 * 4096);
  u16* wot = (u16*)(ws + 25 * MB);      // [25,27) live to end
  u16* qu  = (u16*)(ws + 27 * MB);      // [27,35)
  u16* qv  = (u16*)(ws + 35 * MB);      // [35,43)
  u16* kkp = (u16*)(ws + 43 * MB);      // [43,51)
  u16* vvp = (u16*)(ws + 51 * MB);      // [51,59)
  u16* rrp = (u16*)(ws + 59 * MB);      // [59,63)
  u16* oo  = (u16*)(ws + 63 * MB);      // [63,71)
  float*  Opart  = (float*)(ws + 71 * MB);   // [71,79) f32 O state (GH16)
  float2* mlpart = (float2*)(ws + 79 * MB);  // [79,83) per-lane (m,lacc)
  u16* bdf = (u16*)(ws + 83 * MB);      // [83, 83+8G)
  // pre-main-loop overlays inside bdf region (dead before bdfull writes):
  u16* wqt = (u16*)(ws + 83 * MB);
  u16* wkt = (u16*)(ws + 85 * MB);      // wkt+wvt contiguous for merged K|V GEMM
  u16* wvt = (u16*)(ws + 87 * MB);
  u16* wrt = (u16*)(ws + 89 * MB);
  u16* cpos = (u16*)(ws + 91 * MB);     // [91,95)

  dim3 blk(256);
  k_detect<<<1, 64, 0, stream>>>((const u32*)query, (const u32*)idx, flags);

  {
    SegPack big;
    big.s[0] = { query, cquery, 2 * LQ * HID / 4 };
    big.s[1] = { value, cvalue, 2 * LK * HID / 4 };
    big.s[2] = { pos,   cpos,   RDIM * HID / 4 };
    big.s[3] = { lower, clower, LQ * LK / 4 };
    for (int i = 4; i < 8; ++i) big.s[i] = { nullptr, nullptr, 0 };
    k_ingestN<<<dim3(512, 4), blk, 0, stream>>>(big, flags);
    SegPack sml;
    sml.s[0] = { uw, cuw, NH * DH / 4 };
    sml.s[1] = { vw, cvw, NH * DH / 4 };
    sml.s[2] = { bq, cbq, HID / 4 };
    sml.s[3] = { bk, cbk, HID / 4 };
    sml.s[4] = { bv, cbv, HID / 4 };
    sml.s[5] = { br, cbr, HID / 4 };
    sml.s[6] = { bo, cbo, HID / 4 };
    sml.s[7] = { nullptr, nullptr, 0 };
    k_ingestN<<<dim3(4, 7), blk, 0, stream>>>(sml, flags);
  }
  {
    WPack wp;
    wp.src[0] = Wq; wp.dst[0] = wqt;
    wp.src[1] = Wk; wp.dst[1] = wkt;
    wp.src[2] = Wv; wp.dst[2] = wvt;
    wp.src[3] = Wr; wp.dst[3] = wrt;
    wp.src[4] = Wo; wp.dst[4] = wot;
    k_wtrans<<<dim3(16, 16, 5), blk, 0, stream>>>(wp, flags);
  }

  k_gemm<<<dim3(32, 8), blk, 0, stream>>>(cquery, wqt, cbq, cuw, cvw, qu, qv, 1, nullptr);
  k_gemm<<<dim3(32, 16), blk, 0, stream>>>(cvalue, wkt, cbk, nullptr, nullptr, kkp, vvp, 2, nullptr);
  k_gemm<<<dim3(16, 8), blk, 0, stream>>>(cpos, wrt, cbr, nullptr, nullptr, rrp, nullptr, 1, nullptr);

  k_goff<<<dim3(1024), blk, 0, stream>>>(idx, goff, flags);

  int jSpan16 = 0;
  if (ws_size >= 243 * MB) jSpan16 = 512;        // bdg 32MB [211,243)
  else if (ws_size >= 227 * MB) jSpan16 = 256;   // bdg 16MB [211,227)

  if (jSpan16){
    // GH=16, bdf 128MB [83,211): halves gather point-accesses vs GH=8
    u16* bdg = (u16*)(ws + 211 * MB);
    for (int b0 = 0; b0 < 2 * NH; b0 += 16){
      k_bdfull16<<<dim3(64, 64), blk, 0, stream>>>(qv, rrp, bdf, b0);
      for (int jb = 0; jb < LK; jb += jSpan16){
        k_gather<16><<<dim3(128, jSpan16 / 32), blk, 0, stream>>>(bdf, goff, clower, bdg, jb, jSpan16);
        int mode = (jb == 0 ? 1 : 0) | (jb + jSpan16 >= LK ? 2 : 0);
        k_flash<<<dim3(16, 32), blk, 0, stream>>>(qu, kkp, vvp, bdg, oo, Opart, mlpart, b0, jb, jSpan16, mode);
      }
    }
  } else if (ws_size >= 211 * MB){
    // GH=8: bdf 64MB [83,147), bdg 64MB [147,211)
    u16* bdf8 = bdf;
    u16* bdg = (u16*)(ws + 147 * MB);
    for (int b0 = 0; b0 < 2 * NH; b0 += 8){
      k_bdfull8<<<dim3(64, 32), blk, 0, stream>>>(qv, rrp, bdf8, b0);
      k_gather<8><<<dim3(128, 64), blk, 0, stream>>>(bdf8, goff, clower, bdg, 0, LK);
      k_flash<<<dim3(8, 32), blk, 0, stream>>>(qu, kkp, vvp, bdg, oo, Opart, mlpart, b0, 0, LK, 3);
    }
  } else if (ws_size >= 115 * MB){
    u16* bdg = (u16*)(ws + 99 * MB);
    for (int b0 = 0; b0 < 2 * NH; b0 += 2){
      k_bdfull<2><<<dim3(128, 64), blk, 0, stream>>>(qv, rrp, bdf, b0);
      k_gather<2><<<dim3(128, 64), blk, 0, stream>>>(bdf, goff, clower, bdg, 0, LK);
      k_flash<<<dim3(2, 32), blk, 0, stream>>>(qu, kkp, vvp, bdg, oo, Opart, mlpart, b0, 0, LK, 3);
    }
  } else {
    u16* bdg = (u16*)(ws + 95 * MB);
    for (int b0 = 0; b0 < 2 * NH; b0 += 1){
      k_bdfull<1><<<dim3(128, 64), blk, 0, stream>>>(qv, rrp, bdf, b0);
      k_gather<1><<<dim3(128, 64), blk, 0, stream>>>(bdf, goff, clower, bdg, 0, LK);
      k_flash<<<dim3(1, 32), blk, 0, stream>>>(qu, kkp, vvp, bdg, oo, Opart, mlpart, b0, 0, LK, 3);
    }
  }
  k_gemm<<<dim3(32, 8), blk, 0, stream>>>(oo, wot, cbo, nullptr, nullptr, d_out, nullptr, 0, flags);
}

// Round 16
// 877.088 us; speedup vs baseline: 1.1339x; 1.1339x over previous
//
#include <hip/hip_runtime.h>
#include <stdint.h>

typedef __attribute__((ext_vector_type(8))) short short8;
typedef __attribute__((ext_vector_type(4))) float f32x4;
typedef unsigned short u16;
typedef unsigned int u32;
typedef unsigned long long u64;

#define LQ 2048
#define LK 2048
#define RDIM 2048
#define HID 1024
#define NH 16
#define DH 64
// 0.125 * log2(e): softmax computed in base-2 domain
#define S2SCALE 0.1803368801111204f

__device__ __forceinline__ float bf2f(u16 u){
  union { unsigned int i; float f; } v; v.i = ((unsigned int)u) << 16; return v.f;
}
__device__ __forceinline__ u16 f2bf(float f){
  union { float f; unsigned int i; } v; v.f = f;
  unsigned int r = v.i + 0x7fffu + ((v.i >> 16) & 1u);
  return (u16)(r >> 16);
}
__device__ __forceinline__ f32x4 fzero(){ f32x4 z = {0.0f, 0.0f, 0.0f, 0.0f}; return z; }

// ---------------- dtype detection ----------------
__global__ void k_detect(const u32* __restrict__ q, const u32* __restrict__ idxw,
                         int* __restrict__ flags){
  int t = threadIdx.x;  // 64 threads
  u32 w = q[t];
  int b = (w >> 7) & 0xFF;
  unsigned long long mb = __ballot(b >= 100 && b <= 140);
  u32 hi = idxw[2 * t + 1];
  unsigned long long mi = __ballot(hi == 0u);
  if (t == 0){
    flags[0] = (__popcll(mb) >= 48) ? 1 : 0;
    flags[1] = (__popcll(mi) == 64) ? 1 : 0;
  }
}

// ---------------- batched canonicalize: float tensors -> bf16 ----------------
struct Seg { const void* src; u16* dst; int n4; };
struct SegPack { Seg s[8]; };
__global__ void k_ingestN(SegPack p, const int* __restrict__ flags){
  int f = flags[0];
  Seg sg = p.s[blockIdx.y];
  int stride = gridDim.x * blockDim.x;
  for (int i = blockIdx.x * blockDim.x + threadIdx.x; i < sg.n4; i += stride){
    if (f){
      reinterpret_cast<uint2*>(sg.dst)[i] = reinterpret_cast<const uint2*>(sg.src)[i];
    } else {
      float4 v = reinterpret_cast<const float4*>(sg.src)[i];
      union { u16 h[4]; uint2 u; } t;
      t.h[0] = f2bf(v.x); t.h[1] = f2bf(v.y); t.h[2] = f2bf(v.z); t.h[3] = f2bf(v.w);
      reinterpret_cast<uint2*>(sg.dst)[i] = t.u;
    }
  }
}

// ---------------- fused weight ingest + transpose (5 planes) ----------------
struct WPack { const void* src[5]; u16* dst[5]; };
__global__ void k_wtrans(WPack p, const int* __restrict__ flags){
  int f = flags[0];
  const void* W = p.src[blockIdx.z];
  u16* Wt = p.dst[blockIdx.z];
  __shared__ u16 t[64][65];
  int tid = threadIdx.x;
  int bx = blockIdx.x, by = blockIdx.y;
#pragma unroll
  for (int it = 0; it < 16; ++it){
    int id = it * 256 + tid;
    int r = id >> 6, c = id & 63;
    size_t so = (size_t)(by * 64 + r) * HID + bx * 64 + c;
    t[r][c] = f ? ((const u16*)W)[so] : f2bf(((const float*)W)[so]);
  }
  __syncthreads();
#pragma unroll
  for (int it = 0; it < 16; ++it){
    int id = it * 256 + tid;
    int r = id >> 6, c = id & 63;
    Wt[(size_t)(bx * 64 + r) * HID + by * 64 + c] = t[c][r];
  }
}

// ---------------- gather offsets ----------------
__global__ void k_goff(const int* __restrict__ idx, int* __restrict__ goff,
                       const int* __restrict__ flags){
  int i64f = flags[1];
  const size_t N = (size_t)LQ * LK;
  size_t stride = (size_t)gridDim.x * blockDim.x;
  for (size_t t = (size_t)blockIdx.x * blockDim.x + threadIdx.x; t < N; t += stride){
    long long a0, a1;
    if (i64f){
      const long long* ip = (const long long*)idx;
      a0 = ip[t]; a1 = ip[N + t];
    } else {
      a0 = idx[t]; a1 = idx[N + t];
    }
    goff[t] = (int)(a0 * RDIM + a1);
  }
}

// ---------------- GEMM: D = A[M x 1024] @ Bt^T + bias ----------------
__global__ void k_gemm(const u16* __restrict__ A, const u16* __restrict__ Bt,
                       const u16* __restrict__ bias,
                       const u16* __restrict__ add0, const u16* __restrict__ add1,
                       void* __restrict__ D0, u16* __restrict__ D1,
                       int headmajor, const int* __restrict__ oflags){
  __shared__ u16 As[128][72];
  __shared__ u16 Bs[128][72];
  int tid = threadIdx.x;
  int l = tid & 63, w = tid >> 6;
  int lr = l & 15, g = l >> 4;
  int wr = w >> 1, wc = w & 1;
  int outf32 = oflags ? (oflags[0] == 0) : 0;
  f32x4 acc[4][4];
#pragma unroll
  for (int a = 0; a < 4; ++a)
#pragma unroll
    for (int bq_ = 0; bq_ < 4; ++bq_) acc[a][bq_] = fzero();
  const size_t arowg = (size_t)blockIdx.x * 128;
  const size_t browg = (size_t)blockIdx.y * 128;
  for (int kt = 0; kt < HID; kt += 64){
#pragma unroll
    for (int it = 0; it < 4; ++it){
      int id = it * 256 + tid;
      int r = id >> 3, ch = id & 7;
      uint4 va = *reinterpret_cast<const uint4*>(A + (arowg + r) * HID + kt + ch * 8);
      *reinterpret_cast<uint4*>(&As[r][ch * 8]) = va;
      uint4 vb = *reinterpret_cast<const uint4*>(Bt + (browg + r) * HID + kt + ch * 8);
      *reinterpret_cast<uint4*>(&Bs[r][ch * 8]) = vb;
    }
    __syncthreads();
#pragma unroll
    for (int ks = 0; ks < 2; ++ks){
      short8 af[4], bfv[4];
#pragma unroll
      for (int mf = 0; mf < 4; ++mf)
        af[mf] = *reinterpret_cast<const short8*>(&As[wr * 64 + mf * 16 + lr][ks * 32 + 8 * g]);
#pragma unroll
      for (int nf = 0; nf < 4; ++nf)
        bfv[nf] = *reinterpret_cast<const short8*>(&Bs[wc * 64 + nf * 16 + lr][ks * 32 + 8 * g]);
#pragma unroll
      for (int mf = 0; mf < 4; ++mf)
#pragma unroll
        for (int nf = 0; nf < 4; ++nf)
          acc[mf][nf] = __builtin_amdgcn_mfma_f32_16x16x32_bf16(af[mf], bfv[nf], acc[mf][nf], 0, 0, 0);
    }
    __syncthreads();
  }
#pragma unroll
  for (int mf = 0; mf < 4; ++mf)
#pragma unroll
    for (int nf = 0; nf < 4; ++nf){
      int col = (int)browg + wc * 64 + nf * 16 + lr;
      float bcol = bf2f(bias[col]);
      float a0 = add0 ? bf2f(add0[col]) : 0.0f;
      float a1 = add1 ? bf2f(add1[col]) : 0.0f;
#pragma unroll
      for (int reg = 0; reg < 4; ++reg){
        int row = (int)arowg + wr * 64 + mf * 16 + 4 * g + reg;
        float base = acc[mf][nf][reg] + bcol;
        if (headmajor == 2){
          int b = row >> 11, i = row & 2047;
          int n32 = col >> 6, d = col & 63;
          u16* Dx = (n32 < NH) ? (u16*)D0 : D1;
          size_t dst = ((size_t)(b * NH + (n32 & (NH - 1))) * LQ + i) * DH + d;
          Dx[dst] = f2bf(base);
        } else if (headmajor == 1){
          int b = row >> 11, i = row & 2047;
          int n = col >> 6, d = col & 63;
          size_t dst = ((size_t)(b * NH + n) * LQ + i) * DH + d;
          ((u16*)D0)[dst] = f2bf(base + a0);
          if (D1) D1[dst] = f2bf(base + a1);
        } else {
          size_t dst = (size_t)row * HID + col;
          if (outf32) ((float*)D0)[dst] = base;
          else        ((u16*)D0)[dst] = f2bf(base);
        }
      }
    }
}

// ---------------- BD matrix, G=16: 32i x 64j x 16 heads per block ----------------
// tile layout [i][head][j+pad]: store is 4-way (vs 16-way head-last), writeout packs
// u64 from 4 scalar head reads; global write stays fully contiguous.
__global__ void k_bdfull16(const u16* __restrict__ qv, const u16* __restrict__ rr,
                           u16* __restrict__ bdf, int bnBase){
  __shared__ u16 tile[32][16][72];   // 72 KB
  int tid = threadIdx.x;
  int l = tid & 63, w = tid >> 6;
  int lr = l & 15, g = l >> 4;
  int i0 = blockIdx.x * 32, j0 = blockIdx.y * 64;
#pragma unroll
  for (int hh = 0; hh < 4; ++hh){
    int g_ = w * 4 + hh;
    int bn = bnBase + g_;
    int b = bn >> 4, n = bn & 15;
    const u16* qb = qv + ((size_t)(b * NH + n) * LQ + i0) * DH;
    const u16* rb = rr + ((size_t)n * RDIM + j0) * DH;
    short8 af[2][2];
#pragma unroll
    for (int mf = 0; mf < 2; ++mf)
#pragma unroll
      for (int ks = 0; ks < 2; ++ks)
        af[mf][ks] = *reinterpret_cast<const short8*>(qb + (size_t)(mf * 16 + lr) * DH + ks * 32 + 8 * g);
    f32x4 acc[2][4];
#pragma unroll
    for (int mf = 0; mf < 2; ++mf)
#pragma unroll
      for (int nf = 0; nf < 4; ++nf) acc[mf][nf] = fzero();
#pragma unroll
    for (int nf = 0; nf < 4; ++nf){
#pragma unroll
      for (int ks = 0; ks < 2; ++ks){
        short8 bb = *reinterpret_cast<const short8*>(rb + (size_t)(nf * 16 + lr) * DH + ks * 32 + 8 * g);
#pragma unroll
        for (int mf = 0; mf < 2; ++mf)
          acc[mf][nf] = __builtin_amdgcn_mfma_f32_16x16x32_bf16(af[mf][ks], bb, acc[mf][nf], 0, 0, 0);
      }
    }
#pragma unroll
    for (int mf = 0; mf < 2; ++mf)
#pragma unroll
      for (int nf = 0; nf < 4; ++nf)
#pragma unroll
        for (int reg = 0; reg < 4; ++reg)
          tile[mf * 16 + 4 * g + reg][g_][nf * 16 + lr] = f2bf(acc[mf][nf][reg]);
  }
  __syncthreads();
  // 8192 u64 chunks: pack 4 heads per chunk from scalar reads; contiguous global write
#pragma unroll
  for (int e = 0; e < 32; ++e){
    int id = e * 256 + tid;
    int line = id >> 2, part = id & 3;
    int ii = line >> 6, jj = line & 63;
    union { u16 h[4]; u64 v; } pk;
#pragma unroll
    for (int k = 0; k < 4; ++k) pk.h[k] = tile[ii][part * 4 + k][jj];
    *reinterpret_cast<u64*>(
        bdf + ((size_t)(i0 + ii) * RDIM + (size_t)(j0 + jj)) * 16 + part * 4) = pk.v;
  }
}

// ---------------- BD matrix, 8 heads (fallback tier) ----------------
__global__ void k_bdfull8(const u16* __restrict__ qv, const u16* __restrict__ rr,
                          u16* __restrict__ bdf, int bnBase){
  __shared__ u16 tile[32][64][8];   // 32 KB
  int tid = threadIdx.x;
  int l = tid & 63, w = tid >> 6;
  int lr = l & 15, g = l >> 4;
  int i0 = blockIdx.x * 32, j0 = blockIdx.y * 64;
#pragma unroll
  for (int hh = 0; hh < 2; ++hh){
    int g_ = w * 2 + hh;
    int bn = bnBase + g_;
    int b = bn >> 4, n = bn & 15;
    const u16* qb = qv + ((size_t)(b * NH + n) * LQ + i0) * DH;
    const u16* rb = rr + ((size_t)n * RDIM + j0) * DH;
    short8 af[2][2];
#pragma unroll
    for (int mf = 0; mf < 2; ++mf)
#pragma unroll
      for (int ks = 0; ks < 2; ++ks)
        af[mf][ks] = *reinterpret_cast<const short8*>(qb + (size_t)(mf * 16 + lr) * DH + ks * 32 + 8 * g);
    f32x4 acc[2][4];
#pragma unroll
    for (int mf = 0; mf < 2; ++mf)
#pragma unroll
      for (int nf = 0; nf < 4; ++nf) acc[mf][nf] = fzero();
#pragma unroll
    for (int nf = 0; nf < 4; ++nf){
#pragma unroll
      for (int ks = 0; ks < 2; ++ks){
        short8 bb = *reinterpret_cast<const short8*>(rb + (size_t)(nf * 16 + lr) * DH + ks * 32 + 8 * g);
#pragma unroll
        for (int mf = 0; mf < 2; ++mf)
          acc[mf][nf] = __builtin_amdgcn_mfma_f32_16x16x32_bf16(af[mf][ks], bb, acc[mf][nf], 0, 0, 0);
      }
    }
#pragma unroll
    for (int mf = 0; mf < 2; ++mf)
#pragma unroll
      for (int nf = 0; nf < 4; ++nf)
#pragma unroll
        for (int reg = 0; reg < 4; ++reg)
          tile[mf * 16 + 4 * g + reg][nf * 16 + lr][g_] = f2bf(acc[mf][nf][reg]);
  }
  __syncthreads();
#pragma unroll
  for (int e = 0; e < 16; ++e){
    int id = e * 256 + tid;
    int line = id >> 1, part = id & 1;
    int ii = line >> 6, jj = line & 63;
    u64 v = *reinterpret_cast<const u64*>(&tile[ii][jj][part * 4]);
    *reinterpret_cast<u64*>(
        bdf + ((size_t)(i0 + ii) * RDIM + (size_t)(j0 + jj)) * 8 + part * 4) = v;
  }
}

// ---------------- BD matrix generic fallback (tiny ws) ----------------
template<int G>
__global__ void k_bdfull(const u16* __restrict__ qv, const u16* __restrict__ rr,
                         u16* __restrict__ bdf, int bnBase){
  __shared__ u16 tile[16][32][G];
  int tid = threadIdx.x;
  int l = tid & 63, w = tid >> 6;
  int lr = l & 15, g = l >> 4;
  int i0 = blockIdx.x * 16, j0 = blockIdx.y * 32;
  if (w < G){
    int g_ = w;
    int bn = bnBase + g_;
    int b = bn >> 4, n = bn & 15;
    const u16* qb = qv + ((size_t)(b * NH + n) * LQ + i0) * DH;
    const u16* rb = rr + ((size_t)n * RDIM + j0) * DH;
    f32x4 acc2[2];
    acc2[0] = fzero(); acc2[1] = fzero();
#pragma unroll
    for (int ks = 0; ks < 2; ++ks){
      short8 a = *reinterpret_cast<const short8*>(qb + (size_t)lr * DH + ks * 32 + 8 * g);
#pragma unroll
      for (int nf = 0; nf < 2; ++nf){
        short8 bb = *reinterpret_cast<const short8*>(rb + (size_t)(lr + 16 * nf) * DH + ks * 32 + 8 * g);
        acc2[nf] = __builtin_amdgcn_mfma_f32_16x16x32_bf16(a, bb, acc2[nf], 0, 0, 0);
      }
    }
#pragma unroll
    for (int nf = 0; nf < 2; ++nf){
      int jj = lr + 16 * nf;
#pragma unroll
      for (int reg = 0; reg < 4; ++reg)
        tile[4 * g + reg][jj][g_] = f2bf(acc2[nf][reg]);
    }
  }
  __syncthreads();
  constexpr int CHUNKS = 512;
#pragma unroll
  for (int e = 0; e < (CHUNKS * G + 255) / 256 && e * 256 < CHUNKS * G; ++e){
    int id = e * 256 + tid;
    if (id >= CHUNKS * G) break;
    int line = id / G, k = id % G;
    int ii = line >> 5, jj = line & 31;
    bdf[((size_t)(i0 + ii) * RDIM + (size_t)(j0 + jj)) * G + k] = tile[ii][jj][k];
  }
}

// ---------------- gather + lower mask (NT stores); j-range [jBase, jBase+jSpan) ----------------
template<int G>
__global__ void k_gather(const u16* __restrict__ bdf, const int* __restrict__ goff,
                         const u16* __restrict__ lower, u16* __restrict__ bdg,
                         int jBase, int jSpan){
  __shared__ u16 tile[G][16][32];
  int tid = threadIdx.x;
  int i0 = blockIdx.x * 16;
  int j0loc = blockIdx.y * 32;
  int j0 = jBase + j0loc;
#pragma unroll
  for (int it = 0; it < 2; ++it){
    int p = it * 256 + tid;
    int ii = p >> 5, jj = p & 31;
    size_t off = (size_t)(i0 + ii) * LK + (j0 + jj);
    int go = goff[off];
    float lw = bf2f(lower[off]);
    const u16* src = bdf + (size_t)go * G;
    union { uint4 q[2]; u32 w2[8]; u16 h[16]; } uv;
    if (G == 16){
      uv.q[0] = *reinterpret_cast<const uint4*>(src);
      uv.q[1] = *reinterpret_cast<const uint4*>(src + 8);
    } else if (G == 8){
      uv.q[0] = *reinterpret_cast<const uint4*>(src);
    } else if (G == 2){
      uv.w2[0] = *reinterpret_cast<const u32*>(src);
    } else {
      uv.h[0] = *src;
    }
#pragma unroll
    for (int k = 0; k < G; ++k)
      tile[k][ii][jj] = f2bf(bf2f(uv.h[k]) * lw);
  }
  __syncthreads();
  constexpr int CHUNKS = G * 128;
#pragma unroll
  for (int e = 0; e < (CHUNKS + 255) / 256; ++e){
    int id = e * 256 + tid;
    if (CHUNKS < 256 * ((CHUNKS + 255) / 256) && id >= CHUNKS) break;
    int g_ = id >> 7, rem = id & 127;
    int ii = rem >> 3, part = rem & 7;
    u64 v = *reinterpret_cast<const u64*>(&tile[g_][ii][part * 4]);
    __builtin_nontemporal_store(v, reinterpret_cast<u64*>(
        bdg + (size_t)g_ * LQ * jSpan + (size_t)(i0 + ii) * jSpan + j0loc + part * 4));
  }
}

// ---------------- flash attention: multi-pass over j-sections, carried softmax state ----------------
__device__ __forceinline__ void flash_compute(
    int lr, int g,
    const short8& aq0, const short8& aq1,
    f32x4* O, float* mrun, float* lacc,
    u16 (*klds)[72], u16 (*vtlds)[136], u16 (*pldsw)[136]){
  float sv[8][4];
#pragma unroll
  for (int nf = 0; nf < 8; ++nf){
    f32x4 z = fzero();
    short8 bk0 = *reinterpret_cast<const short8*>(&klds[lr + 16 * nf][8 * g]);
    short8 bk1 = *reinterpret_cast<const short8*>(&klds[lr + 16 * nf][32 + 8 * g]);
    z = __builtin_amdgcn_mfma_f32_16x16x32_bf16(aq0, bk0, z, 0, 0, 0);
    z = __builtin_amdgcn_mfma_f32_16x16x32_bf16(aq1, bk1, z, 0, 0, 0);
#pragma unroll
    for (int reg = 0; reg < 4; ++reg){
      float bd = bf2f(pldsw[4 * g + reg][lr + 16 * nf]);   // BD staged in P-LDS slots
      sv[nf][reg] = (z[reg] + bd) * S2SCALE;
    }
  }
  float fs[4];
#pragma unroll
  for (int reg = 0; reg < 4; ++reg){
    float mx = sv[0][reg];
#pragma unroll
    for (int nf = 1; nf < 8; ++nf) mx = fmaxf(mx, sv[nf][reg]);
#pragma unroll
    for (int d = 1; d < 16; d <<= 1) mx = fmaxf(mx, __shfl_xor(mx, d));
    float mnew = fmaxf(mrun[reg], mx);
    fs[reg] = exp2f(mrun[reg] - mnew);
    mrun[reg] = mnew;
    float sumloc = 0.0f;
#pragma unroll
    for (int nf = 0; nf < 8; ++nf){
      sv[nf][reg] = exp2f(sv[nf][reg] - mnew);
      sumloc += sv[nf][reg];
    }
    lacc[reg] = lacc[reg] * fs[reg] + sumloc;
  }
#pragma unroll
  for (int nf = 0; nf < 4; ++nf)
#pragma unroll
    for (int reg = 0; reg < 4; ++reg)
      O[nf][reg] *= fs[reg];
  // P overwrites the (consumed) BD slots — wave-private region, no barrier needed
#pragma unroll
  for (int nf = 0; nf < 8; ++nf)
#pragma unroll
    for (int reg = 0; reg < 4; ++reg)
      pldsw[4 * g + reg][lr + 16 * nf] = f2bf(sv[nf][reg]);
  short8 pa[4];
#pragma unroll
  for (int ks = 0; ks < 4; ++ks)
    pa[ks] = *reinterpret_cast<const short8*>(&pldsw[lr][ks * 32 + 8 * g]);
#pragma unroll
  for (int nf = 0; nf < 4; ++nf){
    int d = lr + 16 * nf;
#pragma unroll
    for (int ks = 0; ks < 4; ++ks){
      int cv = ((ks * 4 + g) ^ (d >> 3)) * 8;   // V^T chunk swizzle read
      short8 bv = *reinterpret_cast<const short8*>(&vtlds[d][cv]);
      O[nf] = __builtin_amdgcn_mfma_f32_16x16x32_bf16(pa[ks], bv, O[nf], 0, 0, 0);
    }
  }
}

// mode bit0 = first pass (init state), bit1 = last pass (finalize -> oo)
__global__ __launch_bounds__(256) void k_flash(
    const u16* __restrict__ qu, const u16* __restrict__ kk,
    const u16* __restrict__ vv, const u16* __restrict__ bdg,
    u16* __restrict__ oo, float* __restrict__ Opart, float2* __restrict__ mlpart,
    int bnBase, int jBase, int jSpan, int mode){
  __shared__ u16 klds[128][72];
  __shared__ u16 vtlds[64][136];
  __shared__ u16 plds[4][16][136];
  int tid = threadIdx.x;
  int l = tid & 63, w = tid >> 6;
  int lr = l & 15, g = l >> 4;
  int gi = blockIdx.x;
  int bn = bnBase + gi;
  int b = bn >> 4, n = bn & 15;
  int i0 = blockIdx.y * 64;
  const u16* qb = qu + ((size_t)bn * LQ + i0 + w * 16) * DH;
  short8 aq0 = *reinterpret_cast<const short8*>(qb + (size_t)lr * DH + 8 * g);
  short8 aq1 = *reinterpret_cast<const short8*>(qb + (size_t)lr * DH + 32 + 8 * g);
  f32x4 O[4];
  float mrun[4], lacc[4];
  if (mode & 1){
#pragma unroll
    for (int nf = 0; nf < 4; ++nf) O[nf] = fzero();
#pragma unroll
    for (int r = 0; r < 4; ++r){ mrun[r] = -1e30f; lacc[r] = 0.0f; }
  } else {
#pragma unroll
    for (int reg = 0; reg < 4; ++reg){
      int i = i0 + w * 16 + 4 * g + reg;
      float2 ml = mlpart[(((size_t)gi * LQ + i) << 4) + lr];
      mrun[reg] = ml.x; lacc[reg] = ml.y;
#pragma unroll
      for (int nf = 0; nf < 4; ++nf)
        O[nf][reg] = Opart[((size_t)gi * LQ + i) * DH + lr + 16 * nf];
    }
  }
  const u16* kbase = kk + (size_t)bn * LK * DH;
  const u16* vbase = vv + (size_t)bn * LK * DH;
  const u16* bdw = bdg + (size_t)gi * LQ * jSpan + (size_t)(i0 + w * 16) * jSpan;
  u16 (*pldsw)[136] = plds[w];
  int brow = l >> 2, bq = l & 3;   // BD cooperative: 16 rows x 4 lane-quads

  uint4 kv[8];   // K (4) + V (4) staging regs
  uint4 bdv[4];  // BD staging regs (wave's 16 rows x 128 local cols)

#define LOADALL(JL_) do { _Pragma("unroll") for (int it_ = 0; it_ < 4; ++it_){ \
    int id_ = it_ * 256 + tid; int r_ = id_ >> 3, ch_ = id_ & 7; \
    kv[it_]     = *reinterpret_cast<const uint4*>(kbase + (size_t)(jBase + (JL_) + r_) * DH + ch_ * 8); \
    kv[4 + it_] = *reinterpret_cast<const uint4*>(vbase + (size_t)(jBase + (JL_) + r_) * DH + ch_ * 8); } \
    _Pragma("unroll") for (int c_ = 0; c_ < 4; ++c_) \
      bdv[c_] = *reinterpret_cast<const uint4*>(bdw + (size_t)brow * jSpan + (JL_) + (c_ * 4 + bq) * 8); } while(0)

#define WRITEALL() do { _Pragma("unroll") for (int it_ = 0; it_ < 4; ++it_){ \
    int id_ = it_ * 256 + tid; int r_ = id_ >> 3, ch_ = id_ & 7; \
    *reinterpret_cast<uint4*>(&klds[r_][ch_ * 8]) = kv[it_]; \
    u16 tmp_[8]; *reinterpret_cast<uint4*>(tmp_) = kv[4 + it_]; \
    int cb_ = r_ ^ (ch_ * 8); \
    _Pragma("unroll") for (int e_ = 0; e_ < 8; ++e_) vtlds[ch_ * 8 + e_][cb_] = tmp_[e_]; } \
    _Pragma("unroll") for (int c_ = 0; c_ < 4; ++c_) \
      *reinterpret_cast<uint4*>(&pldsw[brow][(c_ * 4 + bq) * 8]) = bdv[c_]; } while(0)

  int ntiles = jSpan >> 7;
  LOADALL(0);
  WRITEALL();
  __syncthreads();

  for (int t = 0; t < ntiles; ++t){
    if (t < ntiles - 1) LOADALL((t + 1) * 128);
    flash_compute(lr, g, aq0, aq1, O, mrun, lacc, klds, vtlds, pldsw);
    if (t < ntiles - 1){
      __syncthreads();
      WRITEALL();
      __syncthreads();
    }
  }
#undef LOADALL
#undef WRITEALL

  if (mode & 2){
    float lsum[4];
#pragma unroll
    for (int reg = 0; reg < 4; ++reg){
      float s = lacc[reg];
#pragma unroll
      for (int d = 1; d < 16; d <<= 1) s += __shfl_xor(s, d);
      lsum[reg] = s;
    }
#pragma unroll
    for (int nf = 0; nf < 4; ++nf)
#pragma unroll
      for (int reg = 0; reg < 4; ++reg){
        int i = i0 + w * 16 + 4 * g + reg;
        float vo = O[nf][reg] / lsum[reg];
        oo[((size_t)(b * LQ + i)) * HID + n * DH + lr + 16 * nf] = f2bf(vo);
      }
  } else {
#pragma unroll
    for (int reg = 0; reg < 4; ++reg){
      int i = i0 + w * 16 + 4 * g + reg;
      float2 ml; ml.x = mrun[reg]; ml.y = lacc[reg];
      mlpart[(((size_t)gi * LQ + i) << 4) + lr] = ml;
#pragma unroll
      for (int nf = 0; nf < 4; ++nf)
        Opart[((size_t)gi * LQ + i) * DH + lr + 16 * nf] = O[nf][reg];
    }
  }
}

extern "C" void kernel_launch(void* const* d_in, const int* in_sizes, int n_in,
                              void* d_out, int out_size, void* d_ws, size_t ws_size,
                              hipStream_t stream){
  const void* query = d_in[0];
  const void* value = d_in[1];
  const void* pos   = d_in[2];
  const void* uw    = d_in[3];
  const void* vw    = d_in[4];
  const int* idx    = (const int*)d_in[5];
  const void* lower = d_in[6];
  const void* Wq = d_in[7];  const void* bq = d_in[8];
  const void* Wk = d_in[9];  const void* bk = d_in[10];
  const void* Wv = d_in[11]; const void* bv = d_in[12];
  const void* Wr = d_in[13]; const void* br = d_in[14];
  const void* Wo = d_in[15]; const void* bo = d_in[16];
  (void)in_sizes; (void)n_in; (void)out_size;

  char* ws = (char*)d_ws;
  const size_t MB = (size_t)1 << 20;
  // ---- layout: fixed region [0,83); bdf [83,211); bdg [211, ...) ----
  u16* cquery = (u16*)(ws + 0 * MB);    // [0,8)   dead after projections
  u16* cvalue = (u16*)(ws + 8 * MB);    // [8,16)  dead after projections
  int* goff   = (int*)(ws + 0 * MB);    // [0,16)  overlays post-projection
  u16* clower = (u16*)(ws + 16 * MB);   // [16,24)
  char* sm = ws + 24 * MB;              // [24,25)
  u16* cuw = (u16*)(sm + 0 * 4096);
  u16* cvw = (u16*)(sm + 1 * 4096);
  u16* cbq = (u16*)(sm + 2 * 4096);
  u16* cbk = (u16*)(sm + 3 * 4096);
  u16* cbv = cbk + 1024;
  u16* cbr = (u16*)(sm + 5 * 4096);
  u16* cbo = (u16*)(sm + 6 * 4096);
  int* flags = (int*)(sm + 7 * 4096);
  u16* wot = (u16*)(ws + 25 * MB);      // [25,27) live to end
  u16* qu  = (u16*)(ws + 27 * MB);      // [27,35)
  u16* qv  = (u16*)(ws + 35 * MB);      // [35,43)
  u16* kkp = (u16*)(ws + 43 * MB);      // [43,51)
  u16* vvp = (u16*)(ws + 51 * MB);      // [51,59)
  u16* rrp = (u16*)(ws + 59 * MB);      // [59,63)
  u16* oo  = (u16*)(ws + 63 * MB);      // [63,71)
  float*  Opart  = (float*)(ws + 71 * MB);   // [71,79) f32 O state (GH16)
  float2* mlpart = (float2*)(ws + 79 * MB);  // [79,83) per-lane (m,lacc)
  u16* bdf = (u16*)(ws + 83 * MB);      // [83, 83+8G)
  // pre-main-loop overlays inside bdf region (dead before bdfull writes):
  u16* wqt = (u16*)(ws + 83 * MB);
  u16* wkt = (u16*)(ws + 85 * MB);      // wkt+wvt contiguous for merged K|V GEMM
  u16* wvt = (u16*)(ws + 87 * MB);
  u16* wrt = (u16*)(ws + 89 * MB);
  u16* cpos = (u16*)(ws + 91 * MB);     // [91,95)

  dim3 blk(256);
  k_detect<<<1, 64, 0, stream>>>((const u32*)query, (const u32*)idx, flags);

  {
    SegPack big;
    big.s[0] = { query, cquery, 2 * LQ * HID / 4 };
    big.s[1] = { value, cvalue, 2 * LK * HID / 4 };
    big.s[2] = { pos,   cpos,   RDIM * HID / 4 };
    big.s[3] = { lower, clower, LQ * LK / 4 };
    for (int i = 4; i < 8; ++i) big.s[i] = { nullptr, nullptr, 0 };
    k_ingestN<<<dim3(512, 4), blk, 0, stream>>>(big, flags);
    SegPack sml;
    sml.s[0] = { uw, cuw, NH * DH / 4 };
    sml.s[1] = { vw, cvw, NH * DH / 4 };
    sml.s[2] = { bq, cbq, HID / 4 };
    sml.s[3] = { bk, cbk, HID / 4 };
    sml.s[4] = { bv, cbv, HID / 4 };
    sml.s[5] = { br, cbr, HID / 4 };
    sml.s[6] = { bo, cbo, HID / 4 };
    sml.s[7] = { nullptr, nullptr, 0 };
    k_ingestN<<<dim3(4, 7), blk, 0, stream>>>(sml, flags);
  }
  {
    WPack wp;
    wp.src[0] = Wq; wp.dst[0] = wqt;
    wp.src[1] = Wk; wp.dst[1] = wkt;
    wp.src[2] = Wv; wp.dst[2] = wvt;
    wp.src[3] = Wr; wp.dst[3] = wrt;
    wp.src[4] = Wo; wp.dst[4] = wot;
    k_wtrans<<<dim3(16, 16, 5), blk, 0, stream>>>(wp, flags);
  }

  k_gemm<<<dim3(32, 8), blk, 0, stream>>>(cquery, wqt, cbq, cuw, cvw, qu, qv, 1, nullptr);
  k_gemm<<<dim3(32, 16), blk, 0, stream>>>(cvalue, wkt, cbk, nullptr, nullptr, kkp, vvp, 2, nullptr);
  k_gemm<<<dim3(16, 8), blk, 0, stream>>>(cpos, wrt, cbr, nullptr, nullptr, rrp, nullptr, 1, nullptr);

  k_goff<<<dim3(1024), blk, 0, stream>>>(idx, goff, flags);

  int jSpan16 = 0;
  if (ws_size >= 243 * MB) jSpan16 = 512;        // bdg 32MB [211,243)
  else if (ws_size >= 227 * MB) jSpan16 = 256;   // bdg 16MB [211,227)

  if (jSpan16){
    // GH=16, bdf 128MB [83,211): halves gather point-accesses vs GH=8
    u16* bdg = (u16*)(ws + 211 * MB);
    for (int b0 = 0; b0 < 2 * NH; b0 += 16){
      k_bdfull16<<<dim3(64, 32), blk, 0, stream>>>(qv, rrp, bdf, b0);
      for (int jb = 0; jb < LK; jb += jSpan16){
        k_gather<16><<<dim3(128, jSpan16 / 32), blk, 0, stream>>>(bdf, goff, clower, bdg, jb, jSpan16);
        int mode = (jb == 0 ? 1 : 0) | (jb + jSpan16 >= LK ? 2 : 0);
        k_flash<<<dim3(16, 32), blk, 0, stream>>>(qu, kkp, vvp, bdg, oo, Opart, mlpart, b0, jb, jSpan16, mode);
      }
    }
  } else if (ws_size >= 211 * MB){
    // GH=8: bdf 64MB [83,147), bdg 64MB [147,211)
    u16* bdf8 = bdf;
    u16* bdg = (u16*)(ws + 147 * MB);
    for (int b0 = 0; b0 < 2 * NH; b0 += 8){
      k_bdfull8<<<dim3(64, 32), blk, 0, stream>>>(qv, rrp, bdf8, b0);
      k_gather<8><<<dim3(128, 64), blk, 0, stream>>>(bdf8, goff, clower, bdg, 0, LK);
      k_flash<<<dim3(8, 32), blk, 0, stream>>>(qu, kkp, vvp, bdg, oo, Opart, mlpart, b0, 0, LK, 3);
    }
  } else if (ws_size >= 115 * MB){
    u16* bdg = (u16*)(ws + 99 * MB);
    for (int b0 = 0; b0 < 2 * NH; b0 += 2){
      k_bdfull<2><<<dim3(128, 64), blk, 0, stream>>>(qv, rrp, bdf, b0);
      k_gather<2><<<dim3(128, 64), blk, 0, stream>>>(bdf, goff, clower, bdg, 0, LK);
      k_flash<<<dim3(2, 32), blk, 0, stream>>>(qu, kkp, vvp, bdg, oo, Opart, mlpart, b0, 0, LK, 3);
    }
  } else {
    u16* bdg = (u16*)(ws + 95 * MB);
    for (int b0 = 0; b0 < 2 * NH; b0 += 1){
      k_bdfull<1><<<dim3(128, 64), blk, 0, stream>>>(qv, rrp, bdf, b0);
      k_gather<1><<<dim3(128, 64), blk, 0, stream>>>(bdf, goff, clower, bdg, 0, LK);
      k_flash<<<dim3(1, 32), blk, 0, stream>>>(qu, kkp, vvp, bdg, oo, Opart, mlpart, b0, 0, LK, 3);
    }
  }
  k_gemm<<<dim3(32, 8), blk, 0, stream>>>(oo, wot, cbo, nullptr, nullptr, d_out, nullptr, 0, flags);
}